// Round 1
// baseline (60.244 us; speedup 1.0000x reference)
//
#include <hip/hip_runtime.h>

#define D 1024
#define T 2048
#define BATCH 4

// workspace float offsets
#define WS_WBAR   0        // 1024 floats: mean_e Wk[e,d]
#define WS_BBAR   1024     // 1 float:     mean(bk)
#define WS_KMEAN  2048     // 8192 floats: kmean[b*T+t]
#define WS_W      10240    // 8192 floats: softmax weights
#define WS_XW     18432    // 4096 floats: sum_t w[b,t]*x[b,t,d]
#define WS_O      22528    // 4096 floats: o[b,d]

// ---- kernel 1: column-mean of Wk (wbar) + mean of bk (bbar) ----
// 64 blocks x 256 threads; block owns 16 consecutive columns d, 16-way split over e.
__global__ void k_wbar(const float* __restrict__ Wk, const float* __restrict__ bk,
                       float* __restrict__ ws) {
    const int dloc = threadIdx.x & 15;
    const int eg   = threadIdx.x >> 4;           // 0..15
    const int d    = blockIdx.x * 16 + dloc;
    float s = 0.f;
    for (int e = eg; e < D; e += 16)
        s += Wk[e * D + d];
    __shared__ float lds[16][17];
    lds[eg][dloc] = s;
    __syncthreads();
    if (threadIdx.x < 16) {
        float t = 0.f;
        #pragma unroll
        for (int i = 0; i < 16; ++i) t += lds[i][threadIdx.x];
        ws[WS_WBAR + blockIdx.x * 16 + threadIdx.x] = t * (1.0f / D);
    }
    if (blockIdx.x == 0) {
        __shared__ float l2[256];
        float sb = bk[threadIdx.x] + bk[threadIdx.x + 256] +
                   bk[threadIdx.x + 512] + bk[threadIdx.x + 768];
        l2[threadIdx.x] = sb;
        __syncthreads();
        for (int off = 128; off > 0; off >>= 1) {
            if (threadIdx.x < off) l2[threadIdx.x] += l2[threadIdx.x + off];
            __syncthreads();
        }
        if (threadIdx.x == 0) ws[WS_BBAR] = l2[0] * (1.0f / D);
    }
}

// ---- kernel 2: kmean[r] = x[r,:]·wbar + bbar ; one wave per row ----
__global__ void __launch_bounds__(256) k_kmean(const float4* __restrict__ x4,
                                               const float* __restrict__ wbar,
                                               const float* __restrict__ bbarp,
                                               float* __restrict__ kmean) {
    const int wave = (int)((blockIdx.x * blockDim.x + threadIdx.x) >> 6); // row 0..8191
    const int lane = threadIdx.x & 63;
    const float4* wbar4 = (const float4*)wbar;
    const float4* xr = x4 + (size_t)wave * (D / 4);
    float acc = 0.f;
    #pragma unroll
    for (int k = 0; k < 4; ++k) {
        float4 xv = xr[lane + k * 64];
        float4 wv = wbar4[lane + k * 64];
        acc += xv.x * wv.x + xv.y * wv.y + xv.z * wv.z + xv.w * wv.w;
    }
    #pragma unroll
    for (int off = 32; off > 0; off >>= 1) acc += __shfl_down(acc, off);
    if (lane == 0) kmean[wave] = acc + bbarp[0];
}

// ---- kernel 3: per-batch softmax of cos(kmean), plus zero xw ----
__global__ void k_softmax(const float* __restrict__ kmean, float* __restrict__ w,
                          float* __restrict__ xw) {
    const int b = blockIdx.x;
    const int tid = threadIdx.x;
    __shared__ float lmax[4], lsum[4];
    float s[8];
    float mx = -1e30f;
    #pragma unroll
    for (int k = 0; k < 8; ++k) {
        s[k] = cosf(kmean[b * T + tid + k * 256]);
        mx = fmaxf(mx, s[k]);
    }
    #pragma unroll
    for (int off = 32; off > 0; off >>= 1) mx = fmaxf(mx, __shfl_down(mx, off));
    if ((tid & 63) == 0) lmax[tid >> 6] = mx;
    __syncthreads();
    mx = fmaxf(fmaxf(lmax[0], lmax[1]), fmaxf(lmax[2], lmax[3]));
    float e[8];
    float sum = 0.f;
    #pragma unroll
    for (int k = 0; k < 8; ++k) { e[k] = expf(s[k] - mx); sum += e[k]; }
    #pragma unroll
    for (int off = 32; off > 0; off >>= 1) sum += __shfl_down(sum, off);
    if ((tid & 63) == 0) lsum[tid >> 6] = sum;
    __syncthreads();
    sum = lsum[0] + lsum[1] + lsum[2] + lsum[3];
    const float inv = 1.0f / sum;
    #pragma unroll
    for (int k = 0; k < 8; ++k) w[b * T + tid + k * 256] = e[k] * inv;
    // zero xw for this batch (runs before kernel 4 in-stream)
    #pragma unroll
    for (int k = 0; k < 4; ++k) xw[b * D + tid + k * 256] = 0.f;
}

// ---- kernel 4: xw[b,d] = sum_t w[b,t] * x[b,t,d]  (t-split + atomics) ----
// grid = BATCH * 64 blocks; block: 256 threads, one float4 of d each, 32 t's.
__global__ void k_xw(const float4* __restrict__ x4, const float* __restrict__ w,
                     float* __restrict__ xw) {
    const int b  = blockIdx.x >> 6;
    const int tc = blockIdx.x & 63;
    const int tid = threadIdx.x;
    float4 acc = {0.f, 0.f, 0.f, 0.f};
    const int t0 = tc * 32;
    for (int t = t0; t < t0 + 32; ++t) {
        const float wt = w[b * T + t];
        const float4 xv = x4[(size_t)(b * T + t) * (D / 4) + tid];
        acc.x += wt * xv.x; acc.y += wt * xv.y;
        acc.z += wt * xv.z; acc.w += wt * xv.w;
    }
    float* dst = xw + b * D + tid * 4;
    atomicAdd(dst + 0, acc.x);
    atomicAdd(dst + 1, acc.y);
    atomicAdd(dst + 2, acc.z);
    atomicAdd(dst + 3, acc.w);
}

// ---- kernel 5: o[b,d] = xw[b,:]·Wv[d,:] + bv[d] ; one wave per row d ----
__global__ void __launch_bounds__(256) k_proj(const float4* __restrict__ Wv4,
                                              const float* __restrict__ xw,
                                              const float* __restrict__ bv,
                                              float* __restrict__ o) {
    const int d    = (int)((blockIdx.x * blockDim.x + threadIdx.x) >> 6); // 0..1023
    const int lane = threadIdx.x & 63;
    const float4* xw4 = (const float4*)xw;
    float a0 = 0.f, a1 = 0.f, a2 = 0.f, a3 = 0.f;
    #pragma unroll
    for (int k = 0; k < 4; ++k) {
        const int idx = lane + k * 64;
        const float4 wv = Wv4[d * (D / 4) + idx];
        const float4 x0 = xw4[idx];
        const float4 x1 = xw4[256 + idx];
        const float4 x2 = xw4[512 + idx];
        const float4 x3 = xw4[768 + idx];
        a0 += wv.x * x0.x + wv.y * x0.y + wv.z * x0.z + wv.w * x0.w;
        a1 += wv.x * x1.x + wv.y * x1.y + wv.z * x1.z + wv.w * x1.w;
        a2 += wv.x * x2.x + wv.y * x2.y + wv.z * x2.z + wv.w * x2.w;
        a3 += wv.x * x3.x + wv.y * x3.y + wv.z * x3.z + wv.w * x3.w;
    }
    #pragma unroll
    for (int off = 32; off > 0; off >>= 1) {
        a0 += __shfl_down(a0, off);
        a1 += __shfl_down(a1, off);
        a2 += __shfl_down(a2, off);
        a3 += __shfl_down(a3, off);
    }
    if (lane == 0) {
        const float bvv = bv[d];
        o[0 * D + d] = a0 + bvv;
        o[1 * D + d] = a1 + bvv;
        o[2 * D + d] = a2 + bvv;
        o[3 * D + d] = a3 + bvv;
    }
}

// ---- kernel 6: out[b,t,d] = o[b,d] broadcast over t ----
__global__ void k_bcast(const float* __restrict__ o, float4* __restrict__ out4) {
    const int n4 = BATCH * T * D / 4;  // 2,097,152
    const float4* o4 = (const float4*)o;
    int idx = blockIdx.x * blockDim.x + threadIdx.x;
    const int stride = gridDim.x * blockDim.x;
    for (int f = idx; f < n4; f += stride) {
        const int d4 = f & 255;        // D/4 = 256
        const int b  = f >> 19;        // T*D/4 = 524288 = 2^19
        out4[f] = o4[(b << 8) + d4];
    }
}

extern "C" void kernel_launch(void* const* d_in, const int* in_sizes, int n_in,
                              void* d_out, int out_size, void* d_ws, size_t ws_size,
                              hipStream_t stream) {
    const float* x  = (const float*)d_in[0];
    // d_in[1] = Wq, d_in[2] = bq : dead code in the reference
    const float* Wk = (const float*)d_in[3];
    const float* bk = (const float*)d_in[4];
    const float* Wv = (const float*)d_in[5];
    const float* bv = (const float*)d_in[6];
    float* ws  = (float*)d_ws;
    float* out = (float*)d_out;

    k_wbar<<<64, 256, 0, stream>>>(Wk, bk, ws);
    k_kmean<<<(BATCH * T) / 4, 256, 0, stream>>>((const float4*)x,
                                                 ws + WS_WBAR, ws + WS_BBAR,
                                                 ws + WS_KMEAN);
    k_softmax<<<BATCH, 256, 0, stream>>>(ws + WS_KMEAN, ws + WS_W, ws + WS_XW);
    k_xw<<<BATCH * 64, 256, 0, stream>>>((const float4*)x, ws + WS_W, ws + WS_XW);
    k_proj<<<(D * 64) / 256, 256, 0, stream>>>((const float4*)Wv, ws + WS_XW, bv,
                                               ws + WS_O);
    k_bcast<<<2048, 256, 0, stream>>>(ws + WS_O, (float4*)out);
}